// Round 1
// baseline (273.229 us; speedup 1.0000x reference)
//
#include <hip/hip_runtime.h>
#include <math.h>

#define B_MAX 512
#define P 196
#define C 80
#define D 512
#define K 16

__device__ __constant__ float d_class_w[7] = {2.5f, 2.0f, 1.0f, 5.0f, 4.0f, 5.0f, 5.0f};
__device__ __constant__ float d_conf[49] = {
    // row-major CONF_MAT[7][7], ones with pairs set
    1,3,2,1,1,2,1,
    3,1,2,1,1,1,1,
    2,2,1,1,1,1,1,
    1,1,1,1,1,1,1,
    1,1,1,1,1,1,2,
    2,1,1,1,1,1,1,
    1,1,1,1,2,1,1};

__device__ __forceinline__ float wave_sum(float v) {
  #pragma unroll
  for (int off = 32; off; off >>= 1) v += __shfl_xor(v, off, 64);
  return v;
}

__device__ __forceinline__ void wave_argmax(float& v, int& idx) {
  #pragma unroll
  for (int off = 1; off < 64; off <<= 1) {
    float ov = __shfl_xor(v, off, 64);
    int oi = __shfl_xor(idx, off, 64);
    if (ov > v || (ov == v && oi < idx)) { v = ov; idx = oi; }
  }
}

__device__ __forceinline__ float dot4(float4 a, float4 b) {
  return a.x*b.x + a.y*b.y + a.z*b.z + a.w*b.w;
}

// ws layout (floats):
// [0]=acc_cls [1]=S_pos [2]=S_neg [3]=cnt_pos [4]=acc_text
// [8..15) wvscale[7]  [16..96) cavscale[80]  [96..176) textscale[80]

__global__ void k_prep(const float* __restrict__ cav, const float* __restrict__ text,
                       const float* __restrict__ wv, float* __restrict__ ws) {
  int tid = threadIdx.x, lane = tid & 63, wave = tid >> 6;
  if (tid < 8) ws[tid] = 0.f;
  float* wvscale = ws + 8;
  float* cavscale = ws + 16;
  float* textscale = ws + 96;
  for (int r = wave; r < 160; r += 4) {
    const float* src = (r < 80) ? cav + (size_t)r * D : text + (size_t)(r - 80) * D;
    float4 a = ((const float4*)src)[lane];
    float4 b = ((const float4*)src)[64 + lane];
    float ss = dot4(a, a) + dot4(b, b);
    ss = wave_sum(ss);
    float n = sqrtf(ss);
    if (lane == 0) {
      if (r < 80) cavscale[r] = 1.f / (n + 1e-8f);
      else        textscale[r - 80] = 1.f / fmaxf(n, 1e-12f);
    }
  }
  if (wave == 0) {
    for (int r = 0; r < 7; r++) {
      float x0 = wv[r * C + lane];
      float x1 = (lane < C - 64) ? wv[r * C + 64 + lane] : 0.f;
      float ss = wave_sum(x0 * x0 + x1 * x1);
      if (lane == 0) wvscale[r] = 1.f / fmaxf(sqrtf(ss), 1e-12f);
    }
  }
}

__global__ void k_cls(const float* __restrict__ logits, const int* __restrict__ labels,
                      int B, float* __restrict__ ws) {
  int i = blockIdx.x * blockDim.x + threadIdx.x;
  float val = 0.f;
  if (i < B) {
    float x[7];
    #pragma unroll
    for (int c = 0; c < 7; c++) x[c] = logits[i * 7 + c];
    int pred = 0; float m = x[0];
    #pragma unroll
    for (int c = 1; c < 7; c++) if (x[c] > m) { m = x[c]; pred = c; }
    float s = 0.f;
    #pragma unroll
    for (int c = 0; c < 7; c++) s += expf(x[c] - m);
    float lse = m + logf(s);
    int l = labels[i];
    float logp_l = x[l] - lse;
    float ce = -logp_l;
    float pt = expf(logp_l);
    float focal = powf(1.f - pt, 2.5f);
    float maxp = expf(m - lse);
    float pen = (maxp < 0.7f) ? 1.5f : 1.f;
    val = 0.25f * focal * ce * d_class_w[l] * d_conf[l * 7 + pred] * pen;
  }
  val = wave_sum(val);
  if ((threadIdx.x & 63) == 0 && val != 0.f) atomicAdd(&ws[0], val);
}

__launch_bounds__(256)
__global__ void k_align(const float* __restrict__ cs, const int* __restrict__ labels,
                        const float* __restrict__ ps, const float* __restrict__ pf,
                        const float* __restrict__ cav, const float* __restrict__ wv,
                        float* __restrict__ ws) {
  __shared__ int topc[16];
  __shared__ int tpi[16][16];
  __shared__ float cols[16][P];
  __shared__ float rnorm[P];
  int b = blockIdx.x;
  int tid = threadIdx.x, lane = tid & 63, wave = tid >> 6;
  const float* wvscale = ws + 8;
  const float* cavscale = ws + 16;

  // 1. top-16 concepts (wave 0)
  if (wave == 0) {
    float v0 = cs[(size_t)b * C + lane];
    float v1 = (lane < C - 64) ? cs[(size_t)b * C + 64 + lane] : -INFINITY;
    int c0 = lane, c1 = 64 + lane;
    for (int j = 0; j < 16; j++) {
      float mv = v0; int mi = c0;
      if (v1 > mv) { mv = v1; mi = c1; }
      wave_argmax(mv, mi);
      if (lane == 0) topc[j] = mi;
      if (mi == c0) v0 = -INFINITY;
      else if (mi == c1) v1 = -INFINITY;
    }
  }
  __syncthreads();

  // 2. stage the 16 needed similarity columns
  for (int idx = tid; idx < 16 * P; idx += 256) {
    int kc = idx / P, p = idx - kc * P;
    cols[kc][p] = ps[((size_t)b * P + p) * C + topc[kc]];
  }
  __syncthreads();

  // 3. top-16 patches for this wave's 4 concepts
  for (int q = 0; q < 4; q++) {
    int kc = wave * 4 + q;
    float v0 = cols[kc][lane];
    float v1 = cols[kc][64 + lane];
    float v2 = cols[kc][128 + lane];
    float v3 = (lane < P - 192) ? cols[kc][192 + lane] : -INFINITY;
    for (int j = 0; j < 16; j++) {
      float mv = v0; int mi = lane;
      if (v1 > mv) { mv = v1; mi = 64 + lane; }
      if (v2 > mv) { mv = v2; mi = 128 + lane; }
      if (v3 > mv) { mv = v3; mi = 192 + lane; }
      wave_argmax(mv, mi);
      if (lane == 0) tpi[kc][j] = mi;
      if (mi == lane) v0 = -INFINITY;
      else if (mi == 64 + lane) v1 = -INFINITY;
      else if (mi == 128 + lane) v2 = -INFINITY;
      else if (mi == 192 + lane) v3 = -INFINITY;
    }
  }

  // 4. row norms for all 196 patches (coalesced full read)
  for (int p = wave; p < P; p += 4) {
    const float4* row = (const float4*)(pf + ((size_t)b * P + p) * D);
    float4 a = row[lane], c = row[64 + lane];
    float ss = wave_sum(dot4(a, a) + dot4(c, c));
    if (lane == 0) rnorm[p] = 1.f / fmaxf(sqrtf(ss), 1e-12f);
  }
  __syncthreads();

  // 5. gather selected rows, mean, cosine sim, align contributions
  float spos = 0.f, sneg = 0.f, cpos = 0.f;
  int l = labels[b];
  for (int q = 0; q < 4; q++) {
    int kc = wave * 4 + q;
    int c = topc[kc];
    float4 a0 = make_float4(0, 0, 0, 0), a1 = make_float4(0, 0, 0, 0);
    for (int j = 0; j < 16; j++) {
      int p = tpi[kc][j];
      float sc = rnorm[p];
      const float4* row = (const float4*)(pf + ((size_t)b * P + p) * D);
      float4 r0 = row[lane], r1 = row[64 + lane];
      a0.x += sc * r0.x; a0.y += sc * r0.y; a0.z += sc * r0.z; a0.w += sc * r0.w;
      a1.x += sc * r1.x; a1.y += sc * r1.y; a1.z += sc * r1.z; a1.w += sc * r1.w;
    }
    const float inv16 = 1.f / 16.f;
    a0.x *= inv16; a0.y *= inv16; a0.z *= inv16; a0.w *= inv16;
    a1.x *= inv16; a1.y *= inv16; a1.z *= inv16; a1.w *= inv16;
    float csc = cavscale[c];
    const float4* crow = (const float4*)(cav + (size_t)c * D);
    float4 c0 = crow[lane], c1 = crow[64 + lane];
    c0.x *= csc; c0.y *= csc; c0.z *= csc; c0.w *= csc;
    c1.x *= csc; c1.y *= csc; c1.z *= csc; c1.w *= csc;
    float num = dot4(a0, c0) + dot4(a1, c1);
    float nm  = dot4(a0, a0) + dot4(a1, a1);
    float nc  = dot4(c0, c0) + dot4(c1, c1);
    #pragma unroll
    for (int off = 1; off < 64; off <<= 1) {
      num += __shfl_xor(num, off, 64);
      nm  += __shfl_xor(nm, off, 64);
      nc  += __shfl_xor(nc, off, 64);
    }
    float sim = num / fmaxf(sqrtf(nm) * sqrtf(nc), 1e-8f);
    if (lane == 0) {
      float dw = wv[l * C + c] * wvscale[l];
      if (dw > 0.1f) { spos += dw * (1.f - sim); cpos += 1.f; }
      else           { sneg += (1.f + sim); }
    }
  }
  if (lane == 0) {
    atomicAdd(&ws[1], spos);
    atomicAdd(&ws[2], sneg);
    atomicAdd(&ws[3], cpos);
  }
}

#define CH 128
__launch_bounds__(256)
__global__ void k_text(const float* __restrict__ cav, const float* __restrict__ text,
                       const int* __restrict__ tki, float* __restrict__ ws) {
  __shared__ int sidx[16];
  __shared__ float scv[16][CH + 4];
  __shared__ float stx[16][CH + 4];
  __shared__ float rowsum[16];
  int b = blockIdx.x, tid = threadIdx.x;
  const float* cavscale = ws + 16;
  const float* textscale = ws + 96;
  if (tid < 16) sidx[tid] = tki[b * 16 + tid];
  __syncthreads();
  int i = tid >> 4, j = tid & 15;
  float dot = 0.f;
  for (int ch = 0; ch < D; ch += CH) {
    for (int t = tid; t < 16 * CH; t += 256) {
      int r = t >> 7, d = t & (CH - 1);
      int idx = sidx[r];
      scv[r][d] = cav[(size_t)idx * D + ch + d] * cavscale[idx];
      stx[r][d] = text[(size_t)idx * D + ch + d] * textscale[idx];
    }
    __syncthreads();
    #pragma unroll 8
    for (int d = 0; d < CH; d += 4) {
      float4 a = *(const float4*)&scv[i][d];
      float4 t4 = *(const float4*)&stx[j][d];
      dot += dot4(a, t4);
    }
    __syncthreads();
  }
  float s = dot / 0.07f;
  s = fminf(fmaxf(s, -100.f), 100.f);
  float m = s;
  #pragma unroll
  for (int off = 1; off < 16; off <<= 1) m = fmaxf(m, __shfl_xor(m, off, 64));
  float e = expf(s - m);
  #pragma unroll
  for (int off = 1; off < 16; off <<= 1) e += __shfl_xor(e, off, 64);
  float lse = m + logf(e);
  float sd = __shfl(s, ((i & 3) << 4) | i, 64);
  if (j == 0) rowsum[i] = lse - sd;
  __syncthreads();
  if (tid == 0) {
    float acc = 0.f;
    #pragma unroll
    for (int r = 0; r < 16; r++) acc += rowsum[r];
    atomicAdd(&ws[4], acc);
  }
}

__global__ void k_final(const float* __restrict__ ws, float* __restrict__ out, int B) {
  float cls = ws[0] / (float)B;
  float cpos = ws[3];
  float total_pairs = (float)B * 16.f;
  float pc = fmaxf(cpos, 1.f);
  float ncnt = fmaxf(total_pairs - cpos, 1.f);
  float align = ws[1] / pc + 0.1f * ws[2] / ncnt;
  float textl = ws[4] / total_pairs;
  out[0] = cls + 0.3f * align + textl;
}

extern "C" void kernel_launch(void* const* d_in, const int* in_sizes, int n_in,
                              void* d_out, int out_size, void* d_ws, size_t ws_size,
                              hipStream_t stream) {
  const float* dl     = (const float*)d_in[0];
  const float* cs     = (const float*)d_in[1];
  const int*   labels = (const int*)d_in[2];
  const float* ps     = (const float*)d_in[3];
  const float* pf     = (const float*)d_in[4];
  const float* cav    = (const float*)d_in[5];
  const float* wv     = (const float*)d_in[6];
  const float* text   = (const float*)d_in[7];
  const int*   tki    = (const int*)d_in[8];
  float* out = (float*)d_out;
  float* ws  = (float*)d_ws;
  int B = in_sizes[0] / 7;

  hipLaunchKernelGGL(k_prep, dim3(1), dim3(256), 0, stream, cav, text, wv, ws);
  hipLaunchKernelGGL(k_cls, dim3((B + 255) / 256), dim3(256), 0, stream, dl, labels, B, ws);
  hipLaunchKernelGGL(k_align, dim3(B), dim3(256), 0, stream, cs, labels, ps, pf, cav, wv, ws);
  hipLaunchKernelGGL(k_text, dim3(B), dim3(256), 0, stream, cav, text, tki, ws);
  hipLaunchKernelGGL(k_final, dim3(1), dim3(1), 0, stream, ws, out, B);
}

// Round 2
// 133.502 us; speedup vs baseline: 2.0466x; 2.0466x over previous
//
#include <hip/hip_runtime.h>
#include <math.h>

#define P 196
#define C 80
#define D 512

// ws float-index layout
#define WS_CLS  0
#define WS_TXT  4
#define WS_WV   8      // 7 floats
#define WS_CAV  16     // 80 floats
#define WS_TEXT 96     // 80 floats
#define WS_SPOS 176    // 64 slots
#define WS_SNEG 240    // 64 slots
#define WS_CPOS 304    // 64 slots
#define WS_NF   368
// byte offsets for u8 index regions
#define WS_TOPC_OFF 2048    // B*16 u8
#define WS_TPI_OFF  16384   // B*16*16 u8

__device__ __constant__ float d_class_w[7] = {2.5f, 2.0f, 1.0f, 5.0f, 4.0f, 5.0f, 5.0f};
__device__ __constant__ float d_conf[49] = {
    1,3,2,1,1,2,1,
    3,1,2,1,1,1,1,
    2,2,1,1,1,1,1,
    1,1,1,1,1,1,1,
    1,1,1,1,1,1,2,
    2,1,1,1,1,1,1,
    1,1,1,1,2,1,1};

__device__ __forceinline__ float wave_sum(float v) {
  #pragma unroll
  for (int off = 32; off; off >>= 1) v += __shfl_xor(v, off, 64);
  return v;
}

__device__ __forceinline__ void wave_argmax(float& v, int& idx) {
  #pragma unroll
  for (int off = 1; off < 64; off <<= 1) {
    float ov = __shfl_xor(v, off, 64);
    int oi = __shfl_xor(idx, off, 64);
    if (ov > v || (ov == v && oi < idx)) { v = ov; idx = oi; }
  }
}

__device__ __forceinline__ float dot4(float4 a, float4 b) {
  return a.x*b.x + a.y*b.y + a.z*b.z + a.w*b.w;
}

__global__ void k_prep(const float* __restrict__ cav, const float* __restrict__ text,
                       const float* __restrict__ wv, float* __restrict__ f) {
  int tid = threadIdx.x, lane = tid & 63, wave = tid >> 6;
  for (int i = tid; i < WS_NF; i += 256) f[i] = 0.f;
  __syncthreads();
  for (int r = wave; r < 160; r += 4) {
    const float* src = (r < 80) ? cav + (size_t)r * D : text + (size_t)(r - 80) * D;
    float4 a = ((const float4*)src)[lane];
    float4 b = ((const float4*)src)[64 + lane];
    float ss = wave_sum(dot4(a, a) + dot4(b, b));
    float n = sqrtf(ss);
    if (lane == 0) {
      if (r < 80) f[WS_CAV + r] = 1.f / (n + 1e-8f);
      else        f[WS_TEXT + r - 80] = 1.f / fmaxf(n, 1e-12f);
    }
  }
  if (wave == 0) {
    for (int r = 0; r < 7; r++) {
      float x0 = wv[r * C + lane];
      float x1 = (lane < C - 64) ? wv[r * C + 64 + lane] : 0.f;
      float ss = wave_sum(x0 * x0 + x1 * x1);
      if (lane == 0) f[WS_WV + r] = 1.f / fmaxf(sqrtf(ss), 1e-12f);
    }
  }
}

__global__ void k_cls(const float* __restrict__ logits, const int* __restrict__ labels,
                      int B, float* __restrict__ f) {
  int i = blockIdx.x * blockDim.x + threadIdx.x;
  float val = 0.f;
  if (i < B) {
    float x[7];
    #pragma unroll
    for (int c = 0; c < 7; c++) x[c] = logits[i * 7 + c];
    int pred = 0; float m = x[0];
    #pragma unroll
    for (int c = 1; c < 7; c++) if (x[c] > m) { m = x[c]; pred = c; }
    float s = 0.f;
    #pragma unroll
    for (int c = 0; c < 7; c++) s += expf(x[c] - m);
    float lse = m + logf(s);
    int l = labels[i];
    float logp_l = x[l] - lse;
    float ce = -logp_l;
    float pt = expf(logp_l);
    float focal = powf(1.f - pt, 2.5f);
    float maxp = expf(m - lse);
    float pen = (maxp < 0.7f) ? 1.5f : 1.f;
    val = 0.25f * focal * ce * d_class_w[l] * d_conf[l * 7 + pred] * pen;
  }
  val = wave_sum(val);
  if ((threadIdx.x & 63) == 0 && val != 0.f) atomicAdd(&f[WS_CLS], val);
}

// Selection: top-16 concepts (wave 0), then one wave per concept for the
// patch top-16. grid = B, 1024 threads (16 waves) -> 32 waves/CU.
__launch_bounds__(1024)
__global__ void k_sel(const float* __restrict__ cs, const float* __restrict__ ps,
                      unsigned char* __restrict__ topc_g, unsigned char* __restrict__ tpi_g) {
  __shared__ int topc_s[16];
  __shared__ float cols[16][P + 4];
  int b = blockIdx.x;
  int tid = threadIdx.x, lane = tid & 63, wave = tid >> 6;

  if (wave == 0) {
    float v0 = cs[(size_t)b * C + lane];
    float v1 = (lane < C - 64) ? cs[(size_t)b * C + 64 + lane] : -INFINITY;
    int c0 = lane, c1 = 64 + lane;
    for (int j = 0; j < 16; j++) {
      float mv = v0; int mi = c0;
      if (v1 > mv) { mv = v1; mi = c1; }
      wave_argmax(mv, mi);
      if (lane == 0) topc_s[j] = mi;
      if (mi == c0) v0 = -INFINITY;
      else if (mi == c1) v1 = -INFINITY;
    }
  }
  __syncthreads();

  for (int t = tid; t < 16 * P; t += 1024) {
    int kc = t / P, p = t - kc * P;
    cols[kc][p] = ps[((size_t)b * P + p) * C + topc_s[kc]];
  }
  __syncthreads();

  int kc = wave;
  float v0 = cols[kc][lane];
  float v1 = cols[kc][64 + lane];
  float v2 = cols[kc][128 + lane];
  float v3 = (lane < P - 192) ? cols[kc][192 + lane] : -INFINITY;
  unsigned char* tp = tpi_g + ((size_t)b * 16 + kc) * 16;
  for (int j = 0; j < 16; j++) {
    float mv = v0; int mi = lane;
    if (v1 > mv) { mv = v1; mi = 64 + lane; }
    if (v2 > mv) { mv = v2; mi = 128 + lane; }
    if (v3 > mv) { mv = v3; mi = 192 + lane; }
    wave_argmax(mv, mi);
    if (lane == 0) tp[j] = (unsigned char)mi;
    if (mi == lane) v0 = -INFINITY;
    else if (mi == 64 + lane) v1 = -INFINITY;
    else if (mi == 128 + lane) v2 = -INFINITY;
    else if (mi == 192 + lane) v3 = -INFINITY;
  }
  if (tid < 16) topc_g[b * 16 + tid] = (unsigned char)topc_s[tid];
}

// Fused gather + on-the-fly norm + mean + cosine. One wave per (b, concept).
// grid = B*4 blocks of 256 (4 waves); XCD-swizzled so the 4 blocks of each b
// share an XCD's L2.
__launch_bounds__(256)
__global__ void k_gather(const int* __restrict__ labels, const float* __restrict__ pf,
                         const float* __restrict__ cav, const float* __restrict__ wv,
                         float* __restrict__ f,
                         const unsigned char* __restrict__ topc_g,
                         const unsigned char* __restrict__ tpi_g, int swz) {
  int idx = blockIdx.x;
  int b, g;
  if (swz) {
    int xcd = idx & 7, rest = idx >> 3;
    g = rest & 3;
    b = (rest >> 2) * 8 + xcd;
  } else {
    b = idx >> 2; g = idx & 3;
  }
  int lane = threadIdx.x & 63, wave = threadIdx.x >> 6;
  int kc = g * 4 + wave;
  int c = topc_g[b * 16 + kc];

  const unsigned int* tp32 = (const unsigned int*)(tpi_g + ((size_t)b * 16 + kc) * 16);
  unsigned int tw0 = tp32[0], tw1 = tp32[1], tw2 = tp32[2], tw3 = tp32[3];

  float4 a0 = make_float4(0, 0, 0, 0), a1 = make_float4(0, 0, 0, 0);
  #pragma unroll
  for (int j = 0; j < 16; j++) {
    unsigned int w = (j < 4) ? tw0 : (j < 8) ? tw1 : (j < 12) ? tw2 : tw3;
    int p = (w >> ((j & 3) * 8)) & 0xFF;
    const float4* row = (const float4*)(pf + ((size_t)b * P + p) * D);
    float4 r0 = row[lane], r1 = row[64 + lane];
    float ss = wave_sum(dot4(r0, r0) + dot4(r1, r1));
    float sc = 1.f / fmaxf(sqrtf(ss), 1e-12f);
    a0.x += sc * r0.x; a0.y += sc * r0.y; a0.z += sc * r0.z; a0.w += sc * r0.w;
    a1.x += sc * r1.x; a1.y += sc * r1.y; a1.z += sc * r1.z; a1.w += sc * r1.w;
  }
  const float inv16 = 1.f / 16.f;
  a0.x *= inv16; a0.y *= inv16; a0.z *= inv16; a0.w *= inv16;
  a1.x *= inv16; a1.y *= inv16; a1.z *= inv16; a1.w *= inv16;

  float csc = f[WS_CAV + c];
  const float4* crow = (const float4*)(cav + (size_t)c * D);
  float4 c0 = crow[lane], c1 = crow[64 + lane];
  c0.x *= csc; c0.y *= csc; c0.z *= csc; c0.w *= csc;
  c1.x *= csc; c1.y *= csc; c1.z *= csc; c1.w *= csc;

  float num = dot4(a0, c0) + dot4(a1, c1);
  float nm  = dot4(a0, a0) + dot4(a1, a1);
  float nc  = dot4(c0, c0) + dot4(c1, c1);
  #pragma unroll
  for (int off = 1; off < 64; off <<= 1) {
    num += __shfl_xor(num, off, 64);
    nm  += __shfl_xor(nm, off, 64);
    nc  += __shfl_xor(nc, off, 64);
  }
  if (lane == 0) {
    float sim = num / fmaxf(sqrtf(nm) * sqrtf(nc), 1e-8f);
    int l = labels[b];
    float dw = wv[l * C + c] * f[WS_WV + l];
    int slot = b & 63;
    if (dw > 0.1f) {
      atomicAdd(&f[WS_SPOS + slot], dw * (1.f - sim));
      atomicAdd(&f[WS_CPOS + slot], 1.f);
    } else {
      atomicAdd(&f[WS_SNEG + slot], 1.f + sim);
    }
  }
}

#define CH 128
__launch_bounds__(256)
__global__ void k_text(const float* __restrict__ cav, const float* __restrict__ text,
                       const int* __restrict__ tki, float* __restrict__ f) {
  __shared__ int sidx[16];
  __shared__ float scv[16][CH + 4];
  __shared__ float stx[16][CH + 4];
  __shared__ float rowsum[16];
  int b = blockIdx.x, tid = threadIdx.x;
  if (tid < 16) sidx[tid] = tki[b * 16 + tid];
  __syncthreads();
  int i = tid >> 4, j = tid & 15;
  float dot = 0.f;
  for (int ch = 0; ch < D; ch += CH) {
    for (int t = tid; t < 16 * CH; t += 256) {
      int r = t >> 7, d = t & (CH - 1);
      int idx = sidx[r];
      scv[r][d] = cav[(size_t)idx * D + ch + d] * f[WS_CAV + idx];
      stx[r][d] = text[(size_t)idx * D + ch + d] * f[WS_TEXT + idx];
    }
    __syncthreads();
    #pragma unroll 8
    for (int d = 0; d < CH; d += 4) {
      float4 a = *(const float4*)&scv[i][d];
      float4 t4 = *(const float4*)&stx[j][d];
      dot += dot4(a, t4);
    }
    __syncthreads();
  }
  float s = dot / 0.07f;
  s = fminf(fmaxf(s, -100.f), 100.f);
  float m = s;
  #pragma unroll
  for (int off = 1; off < 16; off <<= 1) m = fmaxf(m, __shfl_xor(m, off, 64));
  float e = expf(s - m);
  #pragma unroll
  for (int off = 1; off < 16; off <<= 1) e += __shfl_xor(e, off, 64);
  float lse = m + logf(e);
  float sd = __shfl(s, ((i & 3) << 4) | i, 64);
  if (j == 0) rowsum[i] = lse - sd;
  __syncthreads();
  if (tid == 0) {
    float acc = 0.f;
    #pragma unroll
    for (int r = 0; r < 16; r++) acc += rowsum[r];
    atomicAdd(&f[WS_TXT], acc);
  }
}

__global__ void k_final(const float* __restrict__ f, float* __restrict__ out, int B) {
  int lane = threadIdx.x & 63;
  float sp = f[WS_SPOS + lane];
  float sn = f[WS_SNEG + lane];
  float cp = f[WS_CPOS + lane];
  sp = wave_sum(sp); sn = wave_sum(sn); cp = wave_sum(cp);
  if (lane == 0) {
    float cls = f[WS_CLS] / (float)B;
    float total_pairs = (float)B * 16.f;
    float pc = fmaxf(cp, 1.f);
    float ncnt = fmaxf(total_pairs - cp, 1.f);
    float align = sp / pc + 0.1f * sn / ncnt;
    out[0] = cls + 0.3f * align + f[WS_TXT] / total_pairs;
  }
}

extern "C" void kernel_launch(void* const* d_in, const int* in_sizes, int n_in,
                              void* d_out, int out_size, void* d_ws, size_t ws_size,
                              hipStream_t stream) {
  const float* dl     = (const float*)d_in[0];
  const float* cs     = (const float*)d_in[1];
  const int*   labels = (const int*)d_in[2];
  const float* ps     = (const float*)d_in[3];
  const float* pf     = (const float*)d_in[4];
  const float* cav    = (const float*)d_in[5];
  const float* wv     = (const float*)d_in[6];
  const float* text   = (const float*)d_in[7];
  const int*   tki    = (const int*)d_in[8];
  float* out = (float*)d_out;
  float* f   = (float*)d_ws;
  unsigned char* topc_g = (unsigned char*)d_ws + WS_TOPC_OFF;
  unsigned char* tpi_g  = (unsigned char*)d_ws + WS_TPI_OFF;
  int B = in_sizes[0] / 7;
  int swz = (B % 8 == 0) ? 1 : 0;

  hipLaunchKernelGGL(k_prep, dim3(1), dim3(256), 0, stream, cav, text, wv, f);
  hipLaunchKernelGGL(k_cls, dim3((B + 255) / 256), dim3(256), 0, stream, dl, labels, B, f);
  hipLaunchKernelGGL(k_sel, dim3(B), dim3(1024), 0, stream, cs, ps, topc_g, tpi_g);
  hipLaunchKernelGGL(k_gather, dim3(B * 4), dim3(256), 0, stream,
                     labels, pf, cav, wv, f, topc_g, tpi_g, swz);
  hipLaunchKernelGGL(k_text, dim3(B), dim3(256), 0, stream, cav, text, tki, f);
  hipLaunchKernelGGL(k_final, dim3(1), dim3(64), 0, stream, f, out, B);
}

// Round 3
// 94.998 us; speedup vs baseline: 2.8762x; 1.4053x over previous
//
#include <hip/hip_runtime.h>
#include <math.h>

#define P 196
#define C 80
#define D 512

// ws float-index layout
#define WS_CLS  0
#define WS_TXT  4
#define WS_WV   8      // 7 floats
#define WS_CAV  16     // 80 floats
#define WS_TEXT 96     // 80 floats
#define WS_SPOS 176    // 64 slots
#define WS_SNEG 240    // 64 slots
#define WS_CPOS 304    // 64 slots
#define WS_NF   368

__device__ __constant__ float d_class_w[7] = {2.5f, 2.0f, 1.0f, 5.0f, 4.0f, 5.0f, 5.0f};
__device__ __constant__ float d_conf[49] = {
    1,3,2,1,1,2,1,
    3,1,2,1,1,1,1,
    2,2,1,1,1,1,1,
    1,1,1,1,1,1,1,
    1,1,1,1,1,1,2,
    2,1,1,1,1,1,1,
    1,1,1,1,2,1,1};

__device__ __forceinline__ float wave_sum(float v) {
  #pragma unroll
  for (int off = 32; off; off >>= 1) v += __shfl_xor(v, off, 64);
  return v;
}

__device__ __forceinline__ float wave_max(float v) {
  #pragma unroll
  for (int off = 32; off; off >>= 1) v = fmaxf(v, __shfl_xor(v, off, 64));
  return v;
}

__device__ __forceinline__ float dot4(float4 a, float4 b) {
  return a.x*b.x + a.y*b.y + a.z*b.z + a.w*b.w;
}

// grid: 9 blocks x 256. Blocks 0-7: row norms for cav (80) + text (80).
// Block 8: zero accumulators, w_vote norms, cls loss.
__launch_bounds__(256)
__global__ void k_prep(const float* __restrict__ cav, const float* __restrict__ text,
                       const float* __restrict__ wv, const float* __restrict__ logits,
                       const int* __restrict__ labels, int B, float* __restrict__ f) {
  int tid = threadIdx.x, lane = tid & 63, wave = tid >> 6;
  int blk = blockIdx.x;
  if (blk < 8) {
    for (int q = 0; q < 5; q++) {
      int r = blk * 20 + q * 4 + wave;
      const float* src = (r < 80) ? cav + (size_t)r * D : text + (size_t)(r - 80) * D;
      float4 a = ((const float4*)src)[lane];
      float4 b = ((const float4*)src)[64 + lane];
      float ss = wave_sum(dot4(a, a) + dot4(b, b));
      if (lane == 0) {
        if (r < 80) f[WS_CAV + r] = 1.f / (sqrtf(ss) + 1e-8f);
        else        f[WS_TEXT + r - 80] = 1.f / fmaxf(sqrtf(ss), 1e-12f);
      }
    }
    return;
  }
  // block 8: zero accum regions (not the scale regions!)
  __shared__ float part[4];
  for (int i = tid; i < 16; i += 256) f[i] = 0.f;
  for (int i = WS_SPOS + tid; i < WS_NF; i += 256) f[i] = 0.f;
  if (wave == 0 && lane < 64) {
    for (int r = 0; r < 7; r++) {
      float x0 = wv[r * C + lane];
      float x1 = (lane < C - 64) ? wv[r * C + 64 + lane] : 0.f;
      float ss = wave_sum(x0 * x0 + x1 * x1);
      if (lane == 0) f[WS_WV + r] = 1.f / fmaxf(sqrtf(ss), 1e-12f);
    }
  }
  float val = 0.f;
  for (int i = tid; i < B; i += 256) {
    float x[7];
    #pragma unroll
    for (int c = 0; c < 7; c++) x[c] = logits[i * 7 + c];
    int pred = 0; float m = x[0];
    #pragma unroll
    for (int c = 1; c < 7; c++) if (x[c] > m) { m = x[c]; pred = c; }
    float s = 0.f;
    #pragma unroll
    for (int c = 0; c < 7; c++) s += expf(x[c] - m);
    float lse = m + logf(s);
    int l = labels[i];
    float logp_l = x[l] - lse;
    float ce = -logp_l;
    float pt = expf(logp_l);
    float focal = powf(1.f - pt, 2.5f);
    float maxp = expf(m - lse);
    float pen = (maxp < 0.7f) ? 1.5f : 1.f;
    val += 0.25f * focal * ce * d_class_w[l] * d_conf[l * 7 + pred] * pen;
  }
  val = wave_sum(val);
  if (lane == 0) part[wave] = val;
  __syncthreads();
  if (tid == 0) f[WS_CLS] = part[0] + part[1] + part[2] + part[3];
}

// Fused: concept top-16 (wave 0) -> per-wave (one concept each) patch top-16
// with gather+norm+mean+cosine inline. grid = B, 1024 threads (16 waves).
__launch_bounds__(1024)
__global__ void k_main(const float* __restrict__ cs, const int* __restrict__ labels,
                       const float* __restrict__ ps, const float* __restrict__ pf,
                       const float* __restrict__ cav, const float* __restrict__ wv,
                       float* __restrict__ f) {
  __shared__ int topc_s[16];
  int b = blockIdx.x;
  int tid = threadIdx.x, lane = tid & 63, wave = tid >> 6;

  // Phase A: top-16 concepts via ballot-argmax (wave 0 only)
  if (wave == 0) {
    float v0 = cs[(size_t)b * C + lane];
    float v1 = (lane < C - 64) ? cs[(size_t)b * C + 64 + lane] : -INFINITY;
    for (int j = 0; j < 16; j++) {
      float m0 = v0; int i0 = lane;
      if (v1 > m0) { m0 = v1; i0 = 64 + lane; }
      float mv = wave_max(m0);
      unsigned long long mask = __ballot(m0 == mv);
      int l0 = __ffsll(mask) - 1;
      int mi = __shfl(i0, l0, 64);
      if (lane == 0) topc_s[j] = mi;
      if (i0 == mi) { if (mi < 64) v0 = -INFINITY; else v1 = -INFINITY; }
    }
  }
  __syncthreads();

  // Phase B (per wave, concept kc=wave): read sim column into registers,
  // 16 rounds of argmax, gathering the winning pf row each round.
  int kc = wave;
  int c = topc_s[kc];
  const float* col = ps + (size_t)b * P * C + c;
  float v0 = col[(size_t)lane * C];
  float v1 = col[(size_t)(64 + lane) * C];
  float v2 = col[(size_t)(128 + lane) * C];
  float v3 = (lane < P - 192) ? col[(size_t)(192 + lane) * C] : -INFINITY;

  float4 a0 = make_float4(0, 0, 0, 0), a1 = make_float4(0, 0, 0, 0);
  const float4* pfb = (const float4*)(pf + (size_t)b * P * D);
  for (int j = 0; j < 16; j++) {
    float m0 = v0; int i0 = lane;
    if (v1 > m0) { m0 = v1; i0 = 64 + lane; }
    if (v2 > m0) { m0 = v2; i0 = 128 + lane; }
    if (v3 > m0) { m0 = v3; i0 = 192 + lane; }
    float mv = wave_max(m0);
    unsigned long long mask = __ballot(m0 == mv);
    int l0 = __ffsll(mask) - 1;
    int p = __shfl(i0, l0, 64);
    // gather row p
    const float4* row = pfb + (size_t)p * (D / 4);
    float4 r0 = row[lane], r1 = row[64 + lane];
    float ss = wave_sum(dot4(r0, r0) + dot4(r1, r1));
    float sc = 1.f / fmaxf(sqrtf(ss), 1e-12f);
    a0.x += sc * r0.x; a0.y += sc * r0.y; a0.z += sc * r0.z; a0.w += sc * r0.w;
    a1.x += sc * r1.x; a1.y += sc * r1.y; a1.z += sc * r1.z; a1.w += sc * r1.w;
    // exclude winner
    if (i0 == p) {
      if (p == lane) v0 = -INFINITY;
      else if (p == 64 + lane) v1 = -INFINITY;
      else if (p == 128 + lane) v2 = -INFINITY;
      else v3 = -INFINITY;
    }
  }
  const float inv16 = 1.f / 16.f;
  a0.x *= inv16; a0.y *= inv16; a0.z *= inv16; a0.w *= inv16;
  a1.x *= inv16; a1.y *= inv16; a1.z *= inv16; a1.w *= inv16;

  float csc = f[WS_CAV + c];
  const float4* crow = (const float4*)(cav + (size_t)c * D);
  float4 c0 = crow[lane], c1 = crow[64 + lane];
  c0.x *= csc; c0.y *= csc; c0.z *= csc; c0.w *= csc;
  c1.x *= csc; c1.y *= csc; c1.z *= csc; c1.w *= csc;

  float num = dot4(a0, c0) + dot4(a1, c1);
  float nm  = dot4(a0, a0) + dot4(a1, a1);
  float nc  = dot4(c0, c0) + dot4(c1, c1);
  #pragma unroll
  for (int off = 1; off < 64; off <<= 1) {
    num += __shfl_xor(num, off, 64);
    nm  += __shfl_xor(nm, off, 64);
    nc  += __shfl_xor(nc, off, 64);
  }
  if (lane == 0) {
    float sim = num / fmaxf(sqrtf(nm) * sqrtf(nc), 1e-8f);
    int l = labels[b];
    float dw = wv[l * C + c] * f[WS_WV + l];
    int slot = b & 63;
    if (dw > 0.1f) {
      atomicAdd(&f[WS_SPOS + slot], dw * (1.f - sim));
      atomicAdd(&f[WS_CPOS + slot], 1.f);
    } else {
      atomicAdd(&f[WS_SNEG + slot], 1.f + sim);
    }
  }
}

#define CH 128
__launch_bounds__(256)
__global__ void k_text(const float* __restrict__ cav, const float* __restrict__ text,
                       const int* __restrict__ tki, float* __restrict__ f) {
  __shared__ int sidx[16];
  __shared__ float scv[16][CH + 4];
  __shared__ float stx[16][CH + 4];
  __shared__ float rowsum[16];
  int b = blockIdx.x, tid = threadIdx.x;
  if (tid < 16) sidx[tid] = tki[b * 16 + tid];
  __syncthreads();
  int i = tid >> 4, j = tid & 15;
  float dot = 0.f;
  for (int ch = 0; ch < D; ch += CH) {
    for (int t = tid; t < 16 * CH; t += 256) {
      int r = t >> 7, d = t & (CH - 1);
      int idx = sidx[r];
      scv[r][d] = cav[(size_t)idx * D + ch + d] * f[WS_CAV + idx];
      stx[r][d] = text[(size_t)idx * D + ch + d] * f[WS_TEXT + idx];
    }
    __syncthreads();
    #pragma unroll 8
    for (int d = 0; d < CH; d += 4) {
      float4 a = *(const float4*)&scv[i][d];
      float4 t4 = *(const float4*)&stx[j][d];
      dot += dot4(a, t4);
    }
    __syncthreads();
  }
  float s = dot / 0.07f;
  s = fminf(fmaxf(s, -100.f), 100.f);
  float m = s;
  #pragma unroll
  for (int off = 1; off < 16; off <<= 1) m = fmaxf(m, __shfl_xor(m, off, 64));
  float e = expf(s - m);
  #pragma unroll
  for (int off = 1; off < 16; off <<= 1) e += __shfl_xor(e, off, 64);
  float lse = m + logf(e);
  float sd = __shfl(s, ((i & 3) << 4) | i, 64);
  if (j == 0) rowsum[i] = lse - sd;
  __syncthreads();
  if (tid == 0) {
    float acc = 0.f;
    #pragma unroll
    for (int r = 0; r < 16; r++) acc += rowsum[r];
    atomicAdd(&f[WS_TXT], acc);
  }
}

__global__ void k_final(const float* __restrict__ f, float* __restrict__ out, int B) {
  int lane = threadIdx.x & 63;
  float sp = f[WS_SPOS + lane];
  float sn = f[WS_SNEG + lane];
  float cp = f[WS_CPOS + lane];
  sp = wave_sum(sp); sn = wave_sum(sn); cp = wave_sum(cp);
  if (lane == 0) {
    float cls = f[WS_CLS] / (float)B;
    float total_pairs = (float)B * 16.f;
    float pc = fmaxf(cp, 1.f);
    float ncnt = fmaxf(total_pairs - cp, 1.f);
    float align = sp / pc + 0.1f * sn / ncnt;
    out[0] = cls + 0.3f * align + f[WS_TXT] / total_pairs;
  }
}

extern "C" void kernel_launch(void* const* d_in, const int* in_sizes, int n_in,
                              void* d_out, int out_size, void* d_ws, size_t ws_size,
                              hipStream_t stream) {
  const float* dl     = (const float*)d_in[0];
  const float* cs     = (const float*)d_in[1];
  const int*   labels = (const int*)d_in[2];
  const float* ps     = (const float*)d_in[3];
  const float* pf     = (const float*)d_in[4];
  const float* cav    = (const float*)d_in[5];
  const float* wv     = (const float*)d_in[6];
  const float* text   = (const float*)d_in[7];
  const int*   tki    = (const int*)d_in[8];
  float* out = (float*)d_out;
  float* f   = (float*)d_ws;
  int B = in_sizes[0] / 7;

  hipLaunchKernelGGL(k_prep, dim3(9), dim3(256), 0, stream, cav, text, wv, dl, labels, B, f);
  hipLaunchKernelGGL(k_main, dim3(B), dim3(1024), 0, stream, cs, labels, ps, pf, cav, wv, f);
  hipLaunchKernelGGL(k_text, dim3(B), dim3(256), 0, stream, cav, text, tki, f);
  hipLaunchKernelGGL(k_final, dim3(1), dim3(64), 0, stream, f, out, B);
}